// Round 17
// baseline (181.090 us; speedup 1.0000x reference)
//
#include <hip/hip_runtime.h>

#define TPB 256

typedef unsigned int uint32;
typedef unsigned short ushort_t;
typedef __attribute__((ext_vector_type(8))) short bf16x8;
typedef __attribute__((ext_vector_type(4))) float f32x4;

constexpr int NB = 256;  // radix bins (low byte of col)
constexpr int B1 = 256;  // pass-1 blocks

__device__ __forceinline__ uint32 pack_bf16x2(float a, float b) {
  uint32 ua = __float_as_uint(a), ub = __float_as_uint(b);
  ua += 0x7FFFu + ((ua >> 16) & 1u);  // RNE
  ub += 0x7FFFu + ((ub >> 16) & 1u);
  return (ua >> 16) | (ub & 0xFFFF0000u);
}
__device__ __forceinline__ ushort_t bf16_of(float a) {
  uint32 u = __float_as_uint(a);
  u += 0x7FFFu + ((u >> 16) & 1u);
  return (ushort_t)(u >> 16);
}
// packed edge: (src << 15) | (bf16(w) & 0x7FFF)   [w in [0,1) -> sign 0; 0 => w=0]
__device__ __forceinline__ int edge_src(uint32 e) { return (int)(e >> 15); }
__device__ __forceinline__ float edge_w(uint32 e) { return __uint_as_float((e & 0x7FFFu) << 16); }
// byte b of u as float (compiles to v_cvt_f32_ubyteN)
__device__ __forceinline__ float ubf0(uint32 u) { return (float)(u & 0xFFu); }
__device__ __forceinline__ float ubf1(uint32 u) { return (float)((u >> 8) & 0xFFu); }
__device__ __forceinline__ float ubf2(uint32 u) { return (float)((u >> 16) & 0xFFu); }
__device__ __forceinline__ float ubf3(uint32 u) { return (float)((u >> 24) & 0xFFu); }

// ---- pass 1: per-block LDS histogram of col&255 (+ folded W/bias prep) ----
__global__ __launch_bounds__(256) void rx_hist(const int* __restrict__ col,
                                               int* __restrict__ blockhist, int e, int chunk,
                                               const float* __restrict__ W1, ushort_t* __restrict__ Wt1,
                                               const float* __restrict__ W2, ushort_t* __restrict__ Wt2,
                                               const float* __restrict__ b1, float* __restrict__ b1p) {
  __shared__ int h[NB];
  int tid = threadIdx.x, blk = blockIdx.x;
  h[tid] = 0;
  __syncthreads();
  int s = blk * chunk, t = min(e, s + chunk);
  for (int i = s + tid; i < t; i += 256) atomicAdd(&h[col[i] & 255], 1);
  // folded prep (independent work)
  int gtid = blk * 256 + tid;
  if (gtid < 128 * 128) {
    int k = gtid >> 7, m = gtid & 127;
    Wt1[m * 128 + k] = bf16_of(W1[gtid]);
  } else if (gtid < 128 * 128 + 128 * 64) {
    int j = gtid - 128 * 128;
    int k = j >> 6, m = j & 63;
    int kp = ((k & 15) << 3) | (k >> 4);  // permuted K position (matches o1b swizzle)
    Wt2[m * 128 + kp] = bf16_of(W2[j]);
  } else if (gtid < 128 * 128 + 128 * 64 + 128) {
    int p = gtid - (128 * 128 + 128 * 64);
    b1p[p] = b1[16 * (p & 7) + (p >> 3)];
  }
  __syncthreads();
  blockhist[tid * B1 + blk] = h[tid];  // bin-major for scan
}

// ---- 2-kernel scan (block-partial exclusive + bsum scan); consumers add bsum inline ----
__global__ __launch_bounds__(256) void k_scan1(int* __restrict__ a, int* __restrict__ bsum, int n) {
  __shared__ int s[256];
  int tid = threadIdx.x;
  int base = blockIdx.x * 1024 + tid * 4;
  int v0 = 0, v1 = 0, v2 = 0, v3 = 0;
  if (base + 0 < n) v0 = a[base + 0];
  if (base + 1 < n) v1 = a[base + 1];
  if (base + 2 < n) v2 = a[base + 2];
  if (base + 3 < n) v3 = a[base + 3];
  int tsum = v0 + v1 + v2 + v3;
  s[tid] = tsum;
  __syncthreads();
  for (int off = 1; off < 256; off <<= 1) {
    int t = (tid >= off) ? s[tid - off] : 0;
    __syncthreads();
    s[tid] += t;
    __syncthreads();
  }
  if (tid == 255) bsum[blockIdx.x] = s[255];
  int e0 = s[tid] - tsum;
  int e1 = e0 + v0, e2 = e1 + v1, e3 = e2 + v2;
  if (base + 0 < n) a[base + 0] = e0;
  if (base + 1 < n) a[base + 1] = e1;
  if (base + 2 < n) a[base + 2] = e2;
  if (base + 3 < n) a[base + 3] = e3;
}

__global__ __launch_bounds__(256) void k_scan2(int* __restrict__ bsum, int nb) {
  __shared__ int s[256];
  int tid = threadIdx.x;
  int v = (tid < nb) ? bsum[tid] : 0;
  s[tid] = v;
  __syncthreads();
  for (int off = 1; off < 256; off <<= 1) {
    int t = (tid >= off) ? s[tid - off] : 0;
    __syncthreads();
    s[tid] += t;
    __syncthreads();
  }
  if (tid < nb) bsum[tid] = s[tid] - v;  // exclusive
}

// ---- pass 1 scatter: records binned by col&255; rec packed int2 {row|hi<<20, wbits} ----
__global__ __launch_bounds__(256) void rx_scatter1(const int* __restrict__ row,
                                                   const int* __restrict__ col,
                                                   const float* __restrict__ w,
                                                   const int* __restrict__ scanned,
                                                   const int* __restrict__ bsum,
                                                   int2* __restrict__ rec, int e, int chunk) {
  __shared__ int cur[NB];
  int tid = threadIdx.x, blk = blockIdx.x;
  int idx = tid * B1 + blk;
  cur[tid] = scanned[idx] + bsum[idx >> 10];
  __syncthreads();
  int s = blk * chunk, t = min(e, s + chunk);
  for (int i = s + tid; i < t; i += 256) {
    int c = col[i];
    int p = atomicAdd(&cur[c & 255], 1);
    rec[p] = make_int2(row[i] | ((c >> 8) << 20), __float_as_int(w[i]));
  }
}

// ---- pass 2: one block per lo-bin; emits nodeRange {start,count}, dinv, packed edges.
__global__ __launch_bounds__(256) void rx_build(const int2* __restrict__ rec,
                                                const int* __restrict__ scanned,
                                                const int* __restrict__ bsum,
                                                int2* __restrict__ nodeRange,
                                                float* __restrict__ dinv,
                                                uint32* __restrict__ edges, int n, int e) {
  constexpr int NH = 512;
  __shared__ int cnt[NH];
  __shared__ int pref[NH];
  __shared__ int cur[NH];
  __shared__ float dw[NH];
  __shared__ int ssum[256];
  int tid = threadIdx.x, lo = blockIdx.x;
  int si = lo * B1;
  int s = scanned[si] + bsum[si >> 10];
  int t;
  if (lo == NB - 1) t = e;
  else {
    int ti = (lo + 1) * B1;
    t = scanned[ti] + bsum[ti >> 10];
  }
  cnt[tid] = 0; cnt[tid + 256] = 0;
  dw[tid] = 0.f; dw[tid + 256] = 0.f;
  __syncthreads();
  for (int i = s + tid; i < t; i += 256) {
    int2 r = rec[i];
    int hi = ((uint32)r.x) >> 20;
    atomicAdd(&cnt[hi], 1);
    atomicAdd(&dw[hi], __int_as_float(r.y));
  }
  __syncthreads();
  int a0 = cnt[2 * tid], a1 = cnt[2 * tid + 1];
  int sum2 = a0 + a1;
  ssum[tid] = sum2;
  __syncthreads();
  for (int off = 1; off < 256; off <<= 1) {
    int v = (tid >= off) ? ssum[tid - off] : 0;
    __syncthreads();
    ssum[tid] += v;
    __syncthreads();
  }
  int excl = ssum[tid] - sum2;
  pref[2 * tid] = excl;
  pref[2 * tid + 1] = excl + a0;
  __syncthreads();
#pragma unroll
  for (int k = 0; k < 2; ++k) {
    int hi = tid + k * 256;
    int node = (hi << 8) | lo;
    cur[hi] = s + pref[hi];
    if (node < n) {
      nodeRange[node] = make_int2(s + pref[hi], cnt[hi]);
      dinv[node] = rsqrtf(1.0f + dw[hi]);  // self-loop weight 1
    }
  }
  __syncthreads();
  for (int i = s + tid; i < t; i += 256) {
    int2 r = rec[i];
    int hi = ((uint32)r.x) >> 20;
    int p = atomicAdd(&cur[hi], 1);
    uint32 src = (uint32)(r.x & 0x1FFFF);
    uint32 wb = (uint32)bf16_of(__int_as_float(r.y)) & 0x7FFFu;
    edges[p] = (src << 15) | wb;
  }
}

// ---- MFMA GEMM with int8 per-row-scaled output, K=128 fixed.
template <int M, bool XF32, bool SWZ>
__global__ __launch_bounds__(256) void k_gemm_q(
    const void* __restrict__ Xv, const ushort_t* __restrict__ Wt,
    const float* __restrict__ dinv, unsigned char* __restrict__ Hb8,
    float* __restrict__ sc, int n) {
  __shared__ __align__(16) char smem[16384 + M * 256];
  char* Xs = smem;
  char* Ws = smem + 16384;
  const int tid = threadIdx.x;
  const int lane = tid & 63;
  const int w = tid >> 6;
  const int row0 = blockIdx.x * 64;

  {
    const uint4* src = (const uint4*)Wt;
    for (int idx = tid; idx < M * 16; idx += 256) {
      int r = idx >> 4, g = idx & 15;
      uint4 v = src[idx];
      *(uint4*)(Ws + ((r << 8) | ((g << 4) ^ ((r & 7) << 4)))) = v;
    }
  }
  if constexpr (XF32) {
    const float4* src = (const float4*)Xv;
    for (int idx = tid; idx < 64 * 16; idx += 256) {
      int r = idx >> 4, g = idx & 15;
      int grow = row0 + r;
      float4 va = make_float4(0.f, 0.f, 0.f, 0.f), vb = va;
      if (grow < n) {
        va = src[(size_t)grow * 32 + g * 2];
        vb = src[(size_t)grow * 32 + g * 2 + 1];
      }
      uint4 p;
      p.x = pack_bf16x2(va.x, va.y);
      p.y = pack_bf16x2(va.z, va.w);
      p.z = pack_bf16x2(vb.x, vb.y);
      p.w = pack_bf16x2(vb.z, vb.w);
      *(uint4*)(Xs + ((r << 8) | ((g << 4) ^ ((r & 7) << 4)))) = p;
    }
  } else {
    const uint4* src = (const uint4*)Xv;
    for (int idx = tid; idx < 64 * 16; idx += 256) {
      int r = idx >> 4, g = idx & 15;
      int grow = row0 + r;
      uint4 v = make_uint4(0u, 0u, 0u, 0u);
      if (grow < n) v = src[(size_t)grow * 16 + g];
      *(uint4*)(Xs + ((r << 8) | ((g << 4) ^ ((r & 7) << 4)))) = v;
    }
  }
  __syncthreads();

  constexpr int CT = M / 16;
  f32x4 acc[CT];
#pragma unroll
  for (int c = 0; c < CT; ++c) acc[c] = (f32x4){0.f, 0.f, 0.f, 0.f};

  const int arow = (w << 4) | (lane & 15);
  const int kb0 = (lane >> 4) << 4;
#pragma unroll
  for (int ks = 0; ks < 4; ++ks) {
    int kbyte = ks * 64 + kb0;
    bf16x8 a = *(const bf16x8*)(Xs + ((arow << 8) | (kbyte ^ ((arow & 7) << 4))));
#pragma unroll
    for (int c = 0; c < CT; ++c) {
      int brow = c * 16 + (lane & 15);
      bf16x8 b = *(const bf16x8*)(Ws + ((brow << 8) | (kbyte ^ ((brow & 7) << 4))));
      acc[c] = __builtin_amdgcn_mfma_f32_16x16x32_bf16(a, b, acc[c], 0, 0, 0);
    }
  }
  __syncthreads();

  // epilogue: dinv-scale, per-row int8 quantize (u8 = round(v*127/max)+128)
  const int gl = lane & 15;
  const int rbase = (w << 4) | ((lane >> 4) << 2);
  float mx[4] = {0.f, 0.f, 0.f, 0.f};
#pragma unroll
  for (int r = 0; r < 4; ++r) {
    int g = row0 + rbase + r;
    float dv = (g < n) ? dinv[g] : 0.f;
#pragma unroll
    for (int c = 0; c < CT; ++c) {
      acc[c][r] *= dv;
      mx[r] = fmaxf(mx[r], fabsf(acc[c][r]));
    }
  }
#pragma unroll
  for (int off = 1; off < 16; off <<= 1) {
#pragma unroll
    for (int r = 0; r < 4; ++r) mx[r] = fmaxf(mx[r], __shfl_xor(mx[r], off));
  }
  float inv[4];
#pragma unroll
  for (int r = 0; r < 4; ++r) {
    inv[r] = (mx[r] > 1e-30f) ? 127.0f / mx[r] : 0.f;
    int g = row0 + rbase + r;
    if (g < n && gl == 0) sc[g] = mx[r] * (1.0f / 127.0f);
  }

  if constexpr (SWZ) {  // M=128: direct stores, pos = gl*8 + c
#pragma unroll
    for (int r = 0; r < 4; ++r) {
      int g = row0 + rbase + r;
      if (g >= n) continue;
      uint32 lo = 0, hi = 0;
#pragma unroll
      for (int c = 0; c < 4; ++c) {
        uint32 q = (uint32)((int)rintf(acc[c][r] * inv[r]) + 128);
        lo |= q << (8 * c);
      }
#pragma unroll
      for (int c = 4; c < 8; ++c) {
        uint32 q = (uint32)((int)rintf(acc[c][r] * inv[r]) + 128);
        hi |= q << (8 * (c - 4));
      }
      ((uint2*)Hb8)[(size_t)g * 16 + gl] = make_uint2(lo, hi);
    }
  } else {  // M=64: standard order via LDS byte transpose
    unsigned char* Cs = (unsigned char*)smem;  // [64][68]
#pragma unroll
    for (int r = 0; r < 4; ++r) {
#pragma unroll
      for (int c = 0; c < CT; ++c) {
        int q = (int)rintf(acc[c][r] * inv[r]) + 128;
        Cs[(rbase + r) * 68 + c * 16 + gl] = (unsigned char)q;
      }
    }
    __syncthreads();
    for (int idx = tid; idx < 64 * (M / 4); idx += 256) {
      int r = idx / (M / 4), g = idx % (M / 4);
      int grow = row0 + r;
      if (grow < n)
        ((uint32*)Hb8)[(size_t)grow * (M / 4) + g] = *(const uint32*)(Cs + r * 68 + g * 4);
    }
  }
}

// ---- agg layer 1 (C=128, int8 swizzled table): one wave/node, 4 groups x 16 lanes,
// 8 edges per group per iteration (32 edges/wave-iter, all gathers issued up front).
// Edge list in REGISTERS (1 coalesced load) + __shfl broadcast (uniform flow);
// lanes >= cnt hold 0 => weight 0 => padded slots contribute exactly zero.
__global__ __launch_bounds__(TPB) void k_agg128(
    const uint2* __restrict__ t8, const float* __restrict__ scs,
    const uint32* __restrict__ edges, const int2* __restrict__ nodeRange,
    const float* __restrict__ dinv, const float* __restrict__ b1p,
    uint4* __restrict__ out, int n) {
  int node = (blockIdx.x * TPB + threadIdx.x) >> 6;
  if (node >= n) return;
  node = __builtin_amdgcn_readfirstlane(node);
  int lane = threadIdx.x & 63;
  int g = lane >> 4, gl = lane & 15;
  int2 nr = nodeRange[node];
  int s0 = nr.x, cnt = nr.y;
  int nS = min(cnt, 64);
  float di = dinv[node];
  uint32 ev = (lane < nS) ? edges[s0 + lane] : 0u;

  float a0, a1, a2, a3, a4, a5, a6, a7, beta;
  if (g == 0) {  // self loop (weight 1)
    uint2 u = t8[(size_t)node * 16 + gl];
    float al = scs[node];
    beta = al;
    a0 = ubf0(u.x) * al; a1 = ubf1(u.x) * al; a2 = ubf2(u.x) * al; a3 = ubf3(u.x) * al;
    a4 = ubf0(u.y) * al; a5 = ubf1(u.y) * al; a6 = ubf2(u.y) * al; a7 = ubf3(u.y) * al;
  } else {
    beta = 0.f;
    a0 = a1 = a2 = a3 = a4 = a5 = a6 = a7 = 0.f;
  }
  int iters = (nS + 31) >> 5;  // 32 edges per iteration
  for (int it = 0; it < iters; ++it) {
    int k = it * 32 + g;
    uint32 e0 = __shfl(ev, k),      e1 = __shfl(ev, k + 4);
    uint32 e2 = __shfl(ev, k + 8),  e3 = __shfl(ev, k + 12);
    uint32 e4 = __shfl(ev, k + 16), e5 = __shfl(ev, k + 20);
    uint32 e6 = __shfl(ev, k + 24), e7 = __shfl(ev, k + 28);
    int r0 = edge_src(e0), r1 = edge_src(e1), r2 = edge_src(e2), r3 = edge_src(e3);
    int r4 = edge_src(e4), r5 = edge_src(e5), r6 = edge_src(e6), r7 = edge_src(e7);
    uint2 v0 = t8[(size_t)r0 * 16 + gl];
    uint2 v1 = t8[(size_t)r1 * 16 + gl];
    uint2 v2 = t8[(size_t)r2 * 16 + gl];
    uint2 v3 = t8[(size_t)r3 * 16 + gl];
    uint2 v4 = t8[(size_t)r4 * 16 + gl];
    uint2 v5 = t8[(size_t)r5 * 16 + gl];
    uint2 v6 = t8[(size_t)r6 * 16 + gl];
    uint2 v7 = t8[(size_t)r7 * 16 + gl];
    float al0 = edge_w(e0) * scs[r0], al1 = edge_w(e1) * scs[r1];
    float al2 = edge_w(e2) * scs[r2], al3 = edge_w(e3) * scs[r3];
    float al4 = edge_w(e4) * scs[r4], al5 = edge_w(e5) * scs[r5];
    float al6 = edge_w(e6) * scs[r6], al7 = edge_w(e7) * scs[r7];
    beta += ((al0 + al1) + (al2 + al3)) + ((al4 + al5) + (al6 + al7));
    a0 = fmaf(ubf0(v0.x), al0, a0); a1 = fmaf(ubf1(v0.x), al0, a1);
    a2 = fmaf(ubf2(v0.x), al0, a2); a3 = fmaf(ubf3(v0.x), al0, a3);
    a4 = fmaf(ubf0(v0.y), al0, a4); a5 = fmaf(ubf1(v0.y), al0, a5);
    a6 = fmaf(ubf2(v0.y), al0, a6); a7 = fmaf(ubf3(v0.y), al0, a7);
    a0 = fmaf(ubf0(v1.x), al1, a0); a1 = fmaf(ubf1(v1.x), al1, a1);
    a2 = fmaf(ubf2(v1.x), al1, a2); a3 = fmaf(ubf3(v1.x), al1, a3);
    a4 = fmaf(ubf0(v1.y), al1, a4); a5 = fmaf(ubf1(v1.y), al1, a5);
    a6 = fmaf(ubf2(v1.y), al1, a6); a7 = fmaf(ubf3(v1.y), al1, a7);
    a0 = fmaf(ubf0(v2.x), al2, a0); a1 = fmaf(ubf1(v2.x), al2, a1);
    a2 = fmaf(ubf2(v2.x), al2, a2); a3 = fmaf(ubf3(v2.x), al2, a3);
    a4 = fmaf(ubf0(v2.y), al2, a4); a5 = fmaf(ubf1(v2.y), al2, a5);
    a6 = fmaf(ubf2(v2.y), al2, a6); a7 = fmaf(ubf3(v2.y), al2, a7);
    a0 = fmaf(ubf0(v3.x), al3, a0); a1 = fmaf(ubf1(v3.x), al3, a1);
    a2 = fmaf(ubf2(v3.x), al3, a2); a3 = fmaf(ubf3(v3.x), al3, a3);
    a4 = fmaf(ubf0(v3.y), al3, a4); a5 = fmaf(ubf1(v3.y), al3, a5);
    a6 = fmaf(ubf2(v3.y), al3, a6); a7 = fmaf(ubf3(v3.y), al3, a7);
    a0 = fmaf(ubf0(v4.x), al4, a0); a1 = fmaf(ubf1(v4.x), al4, a1);
    a2 = fmaf(ubf2(v4.x), al4, a2); a3 = fmaf(ubf3(v4.x), al4, a3);
    a4 = fmaf(ubf0(v4.y), al4, a4); a5 = fmaf(ubf1(v4.y), al4, a5);
    a6 = fmaf(ubf2(v4.y), al4, a6); a7 = fmaf(ubf3(v4.y), al4, a7);
    a0 = fmaf(ubf0(v5.x), al5, a0); a1 = fmaf(ubf1(v5.x), al5, a1);
    a2 = fmaf(ubf2(v5.x), al5, a2); a3 = fmaf(ubf3(v5.x), al5, a3);
    a4 = fmaf(ubf0(v5.y), al5, a4); a5 = fmaf(ubf1(v5.y), al5, a5);
    a6 = fmaf(ubf2(v5.y), al5, a6); a7 = fmaf(ubf3(v5.y), al5, a7);
    a0 = fmaf(ubf0(v6.x), al6, a0); a1 = fmaf(ubf1(v6.x), al6, a1);
    a2 = fmaf(ubf2(v6.x), al6, a2); a3 = fmaf(ubf3(v6.x), al6, a3);
    a4 = fmaf(ubf0(v6.y), al6, a4); a5 = fmaf(ubf1(v6.y), al6, a5);
    a6 = fmaf(ubf2(v6.y), al6, a6); a7 = fmaf(ubf3(v6.y), al6, a7);
    a0 = fmaf(ubf0(v7.x), al7, a0); a1 = fmaf(ubf1(v7.x), al7, a1);
    a2 = fmaf(ubf2(v7.x), al7, a2); a3 = fmaf(ubf3(v7.x), al7, a3);
    a4 = fmaf(ubf0(v7.y), al7, a4); a5 = fmaf(ubf1(v7.y), al7, a5);
    a6 = fmaf(ubf2(v7.y), al7, a6); a7 = fmaf(ubf3(v7.y), al7, a7);
  }
  for (int kk = s0 + 64 + g; kk < s0 + cnt; kk += 4) {  // rare deg>64 tail
    uint32 e0 = edges[kk];
    int r0 = edge_src(e0);
    uint2 v0 = t8[(size_t)r0 * 16 + gl];
    float al0 = edge_w(e0) * scs[r0];
    beta += al0;
    a0 = fmaf(ubf0(v0.x), al0, a0); a1 = fmaf(ubf1(v0.x), al0, a1);
    a2 = fmaf(ubf2(v0.x), al0, a2); a3 = fmaf(ubf3(v0.x), al0, a3);
    a4 = fmaf(ubf0(v0.y), al0, a4); a5 = fmaf(ubf1(v0.y), al0, a5);
    a6 = fmaf(ubf2(v0.y), al0, a6); a7 = fmaf(ubf3(v0.y), al0, a7);
  }
  a0 += __shfl_xor(a0, 16); a1 += __shfl_xor(a1, 16);
  a2 += __shfl_xor(a2, 16); a3 += __shfl_xor(a3, 16);
  a4 += __shfl_xor(a4, 16); a5 += __shfl_xor(a5, 16);
  a6 += __shfl_xor(a6, 16); a7 += __shfl_xor(a7, 16);
  beta += __shfl_xor(beta, 16);
  a0 += __shfl_xor(a0, 32); a1 += __shfl_xor(a1, 32);
  a2 += __shfl_xor(a2, 32); a3 += __shfl_xor(a3, 32);
  a4 += __shfl_xor(a4, 32); a5 += __shfl_xor(a5, 32);
  a6 += __shfl_xor(a6, 32); a7 += __shfl_xor(a7, 32);
  beta += __shfl_xor(beta, 32);
  if (g == 0) {
    float corr = 128.0f * beta;
    float4 bb0 = ((const float4*)b1p)[gl * 2];
    float4 bb1 = ((const float4*)b1p)[gl * 2 + 1];
    float o0 = fmaxf(fmaf(a0 - corr, di, bb0.x), 0.f);
    float o1 = fmaxf(fmaf(a1 - corr, di, bb0.y), 0.f);
    float o2 = fmaxf(fmaf(a2 - corr, di, bb0.z), 0.f);
    float o3 = fmaxf(fmaf(a3 - corr, di, bb0.w), 0.f);
    float o4 = fmaxf(fmaf(a4 - corr, di, bb1.x), 0.f);
    float o5 = fmaxf(fmaf(a5 - corr, di, bb1.y), 0.f);
    float o6 = fmaxf(fmaf(a6 - corr, di, bb1.z), 0.f);
    float o7 = fmaxf(fmaf(a7 - corr, di, bb1.w), 0.f);
    uint4 ob;
    ob.x = pack_bf16x2(o0, o1);
    ob.y = pack_bf16x2(o2, o3);
    ob.z = pack_bf16x2(o4, o5);
    ob.w = pack_bf16x2(o6, o7);
    out[(size_t)node * 16 + gl] = ob;
  }
}

// ---- agg layer 2 (C=64, int8 standard table): 8 groups x 8 lanes, 4 edges per
// group per iteration (32 edges/wave-iter); register+shfl staging; fp32 out.
__global__ __launch_bounds__(TPB) void k_agg64(
    const uint2* __restrict__ t8, const float* __restrict__ scs,
    const uint32* __restrict__ edges, const int2* __restrict__ nodeRange,
    const float* __restrict__ dinv, const float* __restrict__ bias,
    float4* __restrict__ out, int n) {
  int node = (blockIdx.x * TPB + threadIdx.x) >> 6;
  if (node >= n) return;
  node = __builtin_amdgcn_readfirstlane(node);
  int lane = threadIdx.x & 63;
  int g = lane >> 3, gl = lane & 7;
  int2 nr = nodeRange[node];
  int s0 = nr.x, cnt = nr.y;
  int nS = min(cnt, 64);
  float di = dinv[node];
  uint32 ev = (lane < nS) ? edges[s0 + lane] : 0u;

  float a0, a1, a2, a3, a4, a5, a6, a7, beta;
  if (g == 0) {  // self loop
    uint2 u = t8[(size_t)node * 8 + gl];
    float al = scs[node];
    beta = al;
    a0 = ubf0(u.x) * al; a1 = ubf1(u.x) * al; a2 = ubf2(u.x) * al; a3 = ubf3(u.x) * al;
    a4 = ubf0(u.y) * al; a5 = ubf1(u.y) * al; a6 = ubf2(u.y) * al; a7 = ubf3(u.y) * al;
  } else {
    beta = 0.f;
    a0 = a1 = a2 = a3 = a4 = a5 = a6 = a7 = 0.f;
  }
  int iters = (nS + 31) >> 5;  // 32 edges per iteration
  for (int it = 0; it < iters; ++it) {
    int k = it * 32 + g;
    uint32 e0 = __shfl(ev, k),      e1 = __shfl(ev, k + 8);
    uint32 e2 = __shfl(ev, k + 16), e3 = __shfl(ev, k + 24);
    int r0 = edge_src(e0), r1 = edge_src(e1), r2 = edge_src(e2), r3 = edge_src(e3);
    uint2 v0 = t8[(size_t)r0 * 8 + gl];
    uint2 v1 = t8[(size_t)r1 * 8 + gl];
    uint2 v2 = t8[(size_t)r2 * 8 + gl];
    uint2 v3 = t8[(size_t)r3 * 8 + gl];
    float al0 = edge_w(e0) * scs[r0], al1 = edge_w(e1) * scs[r1];
    float al2 = edge_w(e2) * scs[r2], al3 = edge_w(e3) * scs[r3];
    beta += (al0 + al1) + (al2 + al3);
    a0 = fmaf(ubf0(v0.x), al0, a0); a1 = fmaf(ubf1(v0.x), al0, a1);
    a2 = fmaf(ubf2(v0.x), al0, a2); a3 = fmaf(ubf3(v0.x), al0, a3);
    a4 = fmaf(ubf0(v0.y), al0, a4); a5 = fmaf(ubf1(v0.y), al0, a5);
    a6 = fmaf(ubf2(v0.y), al0, a6); a7 = fmaf(ubf3(v0.y), al0, a7);
    a0 = fmaf(ubf0(v1.x), al1, a0); a1 = fmaf(ubf1(v1.x), al1, a1);
    a2 = fmaf(ubf2(v1.x), al1, a2); a3 = fmaf(ubf3(v1.x), al1, a3);
    a4 = fmaf(ubf0(v1.y), al1, a4); a5 = fmaf(ubf1(v1.y), al1, a5);
    a6 = fmaf(ubf2(v1.y), al1, a6); a7 = fmaf(ubf3(v1.y), al1, a7);
    a0 = fmaf(ubf0(v2.x), al2, a0); a1 = fmaf(ubf1(v2.x), al2, a1);
    a2 = fmaf(ubf2(v2.x), al2, a2); a3 = fmaf(ubf3(v2.x), al2, a3);
    a4 = fmaf(ubf0(v2.y), al2, a4); a5 = fmaf(ubf1(v2.y), al2, a5);
    a6 = fmaf(ubf2(v2.y), al2, a6); a7 = fmaf(ubf3(v2.y), al2, a7);
    a0 = fmaf(ubf0(v3.x), al3, a0); a1 = fmaf(ubf1(v3.x), al3, a1);
    a2 = fmaf(ubf2(v3.x), al3, a2); a3 = fmaf(ubf3(v3.x), al3, a3);
    a4 = fmaf(ubf0(v3.y), al3, a4); a5 = fmaf(ubf1(v3.y), al3, a5);
    a6 = fmaf(ubf2(v3.y), al3, a6); a7 = fmaf(ubf3(v3.y), al3, a7);
  }
  for (int kk = s0 + 64 + g; kk < s0 + cnt; kk += 8) {  // rare deg>64 tail
    uint32 e0 = edges[kk];
    int r0 = edge_src(e0);
    uint2 v0 = t8[(size_t)r0 * 8 + gl];
    float al0 = edge_w(e0) * scs[r0];
    beta += al0;
    a0 = fmaf(ubf0(v0.x), al0, a0); a1 = fmaf(ubf1(v0.x), al0, a1);
    a2 = fmaf(ubf2(v0.x), al0, a2); a3 = fmaf(ubf3(v0.x), al0, a3);
    a4 = fmaf(ubf0(v0.y), al0, a4); a5 = fmaf(ubf1(v0.y), al0, a5);
    a6 = fmaf(ubf2(v0.y), al0, a6); a7 = fmaf(ubf3(v0.y), al0, a7);
  }
#pragma unroll
  for (int off = 8; off <= 32; off <<= 1) {
    a0 += __shfl_xor(a0, off); a1 += __shfl_xor(a1, off);
    a2 += __shfl_xor(a2, off); a3 += __shfl_xor(a3, off);
    a4 += __shfl_xor(a4, off); a5 += __shfl_xor(a5, off);
    a6 += __shfl_xor(a6, off); a7 += __shfl_xor(a7, off);
    beta += __shfl_xor(beta, off);
  }
  if (g == 0) {
    float corr = 128.0f * beta;
    float4 bb0 = ((const float4*)bias)[gl * 2];
    float4 bb1 = ((const float4*)bias)[gl * 2 + 1];
    float4 o0, o1;
    o0.x = fmaxf(fmaf(a0 - corr, di, bb0.x), 0.f);
    o0.y = fmaxf(fmaf(a1 - corr, di, bb0.y), 0.f);
    o0.z = fmaxf(fmaf(a2 - corr, di, bb0.z), 0.f);
    o0.w = fmaxf(fmaf(a3 - corr, di, bb0.w), 0.f);
    o1.x = fmaxf(fmaf(a4 - corr, di, bb1.x), 0.f);
    o1.y = fmaxf(fmaf(a5 - corr, di, bb1.y), 0.f);
    o1.z = fmaxf(fmaf(a6 - corr, di, bb1.z), 0.f);
    o1.w = fmaxf(fmaf(a7 - corr, di, bb1.w), 0.f);
    out[(size_t)node * 16 + gl * 2] = o0;
    out[(size_t)node * 16 + gl * 2 + 1] = o1;
  }
}

extern "C" void kernel_launch(void* const* d_in, const int* in_sizes, int n_in,
                              void* d_out, int out_size, void* d_ws, size_t ws_size,
                              hipStream_t stream) {
  const float* x  = (const float*)d_in[0];
  const int*   ei = (const int*)d_in[1];
  const float* ew = (const float*)d_in[2];
  const float* W1 = (const float*)d_in[3];
  const float* b1 = (const float*)d_in[4];
  const float* W2 = (const float*)d_in[5];
  const float* b2 = (const float*)d_in[6];
  float* out = (float*)d_out;

  constexpr int IN_C = 128, HID = 128, OUTC = 64;
  const int n = in_sizes[0] / IN_C;
  const int e = in_sizes[2];
  const int* rowp = ei;
  const int* colp = ei + e;

  auto cdiv = [](long a, long b) { return (int)((a + b - 1) / b); };
  auto align = [](size_t v) { return (v + 255) & ~(size_t)255; };

  char* ws = (char*)d_ws;
  size_t o = 0;
  int*      blockhist = (int*)(ws + o);      o = align(o + (size_t)NB * B1 * 4);
  int*      bsum      = (int*)(ws + o);      o = align(o + 4096);
  float*    dinv      = (float*)(ws + o);    o = align(o + (size_t)n * 4);
  int2*     nodeRange = (int2*)(ws + o);     o = align(o + (size_t)n * 8);
  ushort_t* Wt1       = (ushort_t*)(ws + o); o = align(o + (size_t)HID * IN_C * 2);
  ushort_t* Wt2       = (ushort_t*)(ws + o); o = align(o + (size_t)OUTC * HID * 2);
  float*    b1p       = (float*)(ws + o);    o = align(o + 512);
  float*    sc1       = (float*)(ws + o);    o = align(o + (size_t)n * 4);
  float*    sc2       = (float*)(ws + o);    o = align(o + (size_t)n * 4);
  int2*     rec       = (int2*)(ws + o);     o = align(o + (size_t)e * 8);
  uint32*   edges     = (uint32*)(ws + o);   o = align(o + (size_t)e * 4);
  unsigned char* hs1b8 = (unsigned char*)(ws + o); o = align(o + (size_t)n * HID);  // int8 swz
  uint4*    o1b       = (uint4*)(ws + o);    o = align(o + (size_t)n * HID * 2);    // bf16 swz
  unsigned char* hs2b8 = hs1b8;  // int8 [n][64]; hs1b8 dead after agg128

  const int chunk = cdiv(e, B1);
  const int nscan = NB * B1;  // 65536

  // ---- preprocessing: CSR build (zero global atomics), W/bias prep folded ----
  rx_hist<<<B1, 256, 0, stream>>>(colp, blockhist, e, chunk, W1, Wt1, W2, Wt2, b1, b1p);
  k_scan1<<<nscan / 1024, 256, 0, stream>>>(blockhist, bsum, nscan);
  k_scan2<<<1, 256, 0, stream>>>(bsum, nscan / 1024);
  rx_scatter1<<<B1, 256, 0, stream>>>(rowp, colp, ew, blockhist, bsum, rec, e, chunk);
  rx_build<<<NB, 256, 0, stream>>>(rec, blockhist, bsum, nodeRange, dinv, edges, n, e);

  // ---- layer 1 ----
  k_gemm_q<HID, true, true><<<cdiv(n, 64), 256, 0, stream>>>(x, Wt1, dinv, hs1b8, sc1, n);
  k_agg128<<<cdiv(n, 4), TPB, 0, stream>>>((const uint2*)hs1b8, sc1, edges, nodeRange,
                                           dinv, b1p, o1b, n);

  // ---- layer 2 ----
  k_gemm_q<OUTC, false, false><<<cdiv(n, 64), 256, 0, stream>>>(o1b, Wt2, dinv, hs2b8, sc2, n);
  k_agg64<<<cdiv(n, 4), TPB, 0, stream>>>((const uint2*)hs2b8, sc2, edges, nodeRange,
                                          dinv, b2, (float4*)out, n);
}

// Round 18
// 175.308 us; speedup vs baseline: 1.0330x; 1.0330x over previous
//
#include <hip/hip_runtime.h>

#define TPB 256

typedef unsigned int uint32;
typedef unsigned short ushort_t;
typedef __attribute__((ext_vector_type(8))) short bf16x8;
typedef __attribute__((ext_vector_type(4))) float f32x4;

constexpr int NB = 256;  // radix bins (low byte of col)
constexpr int B1 = 256;  // pass-1 blocks

__device__ __forceinline__ uint32 pack_bf16x2(float a, float b) {
  uint32 ua = __float_as_uint(a), ub = __float_as_uint(b);
  ua += 0x7FFFu + ((ua >> 16) & 1u);  // RNE
  ub += 0x7FFFu + ((ub >> 16) & 1u);
  return (ua >> 16) | (ub & 0xFFFF0000u);
}
__device__ __forceinline__ ushort_t bf16_of(float a) {
  uint32 u = __float_as_uint(a);
  u += 0x7FFFu + ((u >> 16) & 1u);
  return (ushort_t)(u >> 16);
}
// packed edge: (src << 15) | (bf16(w) & 0x7FFF)   [w in [0,1) -> sign 0; 0 => w=0]
__device__ __forceinline__ int edge_src(uint32 e) { return (int)(e >> 15); }
__device__ __forceinline__ float edge_w(uint32 e) { return __uint_as_float((e & 0x7FFFu) << 16); }
// byte b of u as float (compiles to v_cvt_f32_ubyteN)
__device__ __forceinline__ float ubf0(uint32 u) { return (float)(u & 0xFFu); }
__device__ __forceinline__ float ubf1(uint32 u) { return (float)((u >> 8) & 0xFFu); }
__device__ __forceinline__ float ubf2(uint32 u) { return (float)((u >> 16) & 0xFFu); }
__device__ __forceinline__ float ubf3(uint32 u) { return (float)((u >> 24) & 0xFFu); }

// ---- pass 1: per-block LDS histogram of col&255 (+ folded W/bias prep) ----
__global__ __launch_bounds__(256) void rx_hist(const int* __restrict__ col,
                                               int* __restrict__ blockhist, int e, int chunk,
                                               const float* __restrict__ W1, ushort_t* __restrict__ Wt1,
                                               const float* __restrict__ W2, ushort_t* __restrict__ Wt2,
                                               const float* __restrict__ b1, float* __restrict__ b1p) {
  __shared__ int h[NB];
  int tid = threadIdx.x, blk = blockIdx.x;
  h[tid] = 0;
  __syncthreads();
  int s = blk * chunk, t = min(e, s + chunk);
  for (int i = s + tid; i < t; i += 256) atomicAdd(&h[col[i] & 255], 1);
  // folded prep (independent work)
  int gtid = blk * 256 + tid;
  if (gtid < 128 * 128) {
    int k = gtid >> 7, m = gtid & 127;
    Wt1[m * 128 + k] = bf16_of(W1[gtid]);
  } else if (gtid < 128 * 128 + 128 * 64) {
    int j = gtid - 128 * 128;
    int k = j >> 6, m = j & 63;
    int kp = ((k & 15) << 3) | (k >> 4);  // permuted K position (matches o1b swizzle)
    Wt2[m * 128 + kp] = bf16_of(W2[j]);
  } else if (gtid < 128 * 128 + 128 * 64 + 128) {
    int p = gtid - (128 * 128 + 128 * 64);
    b1p[p] = b1[16 * (p & 7) + (p >> 3)];
  }
  __syncthreads();
  blockhist[tid * B1 + blk] = h[tid];  // bin-major for scan
}

// ---- 2-kernel scan (block-partial exclusive + bsum scan); consumers add bsum inline ----
__global__ __launch_bounds__(256) void k_scan1(int* __restrict__ a, int* __restrict__ bsum, int n) {
  __shared__ int s[256];
  int tid = threadIdx.x;
  int base = blockIdx.x * 1024 + tid * 4;
  int v0 = 0, v1 = 0, v2 = 0, v3 = 0;
  if (base + 0 < n) v0 = a[base + 0];
  if (base + 1 < n) v1 = a[base + 1];
  if (base + 2 < n) v2 = a[base + 2];
  if (base + 3 < n) v3 = a[base + 3];
  int tsum = v0 + v1 + v2 + v3;
  s[tid] = tsum;
  __syncthreads();
  for (int off = 1; off < 256; off <<= 1) {
    int t = (tid >= off) ? s[tid - off] : 0;
    __syncthreads();
    s[tid] += t;
    __syncthreads();
  }
  if (tid == 255) bsum[blockIdx.x] = s[255];
  int e0 = s[tid] - tsum;
  int e1 = e0 + v0, e2 = e1 + v1, e3 = e2 + v2;
  if (base + 0 < n) a[base + 0] = e0;
  if (base + 1 < n) a[base + 1] = e1;
  if (base + 2 < n) a[base + 2] = e2;
  if (base + 3 < n) a[base + 3] = e3;
}

__global__ __launch_bounds__(256) void k_scan2(int* __restrict__ bsum, int nb) {
  __shared__ int s[256];
  int tid = threadIdx.x;
  int v = (tid < nb) ? bsum[tid] : 0;
  s[tid] = v;
  __syncthreads();
  for (int off = 1; off < 256; off <<= 1) {
    int t = (tid >= off) ? s[tid - off] : 0;
    __syncthreads();
    s[tid] += t;
    __syncthreads();
  }
  if (tid < nb) bsum[tid] = s[tid] - v;  // exclusive
}

// ---- pass 1 scatter: records binned by col&255; rec packed int2 {row|hi<<20, wbits} ----
__global__ __launch_bounds__(256) void rx_scatter1(const int* __restrict__ row,
                                                   const int* __restrict__ col,
                                                   const float* __restrict__ w,
                                                   const int* __restrict__ scanned,
                                                   const int* __restrict__ bsum,
                                                   int2* __restrict__ rec, int e, int chunk) {
  __shared__ int cur[NB];
  int tid = threadIdx.x, blk = blockIdx.x;
  int idx = tid * B1 + blk;
  cur[tid] = scanned[idx] + bsum[idx >> 10];
  __syncthreads();
  int s = blk * chunk, t = min(e, s + chunk);
  for (int i = s + tid; i < t; i += 256) {
    int c = col[i];
    int p = atomicAdd(&cur[c & 255], 1);
    rec[p] = make_int2(row[i] | ((c >> 8) << 20), __float_as_int(w[i]));
  }
}

// ---- pass 2: one block per lo-bin; emits nodeRange {start,count}, dinv, packed edges.
__global__ __launch_bounds__(256) void rx_build(const int2* __restrict__ rec,
                                                const int* __restrict__ scanned,
                                                const int* __restrict__ bsum,
                                                int2* __restrict__ nodeRange,
                                                float* __restrict__ dinv,
                                                uint32* __restrict__ edges, int n, int e) {
  constexpr int NH = 512;
  __shared__ int cnt[NH];
  __shared__ int pref[NH];
  __shared__ int cur[NH];
  __shared__ float dw[NH];
  __shared__ int ssum[256];
  int tid = threadIdx.x, lo = blockIdx.x;
  int si = lo * B1;
  int s = scanned[si] + bsum[si >> 10];
  int t;
  if (lo == NB - 1) t = e;
  else {
    int ti = (lo + 1) * B1;
    t = scanned[ti] + bsum[ti >> 10];
  }
  cnt[tid] = 0; cnt[tid + 256] = 0;
  dw[tid] = 0.f; dw[tid + 256] = 0.f;
  __syncthreads();
  for (int i = s + tid; i < t; i += 256) {
    int2 r = rec[i];
    int hi = ((uint32)r.x) >> 20;
    atomicAdd(&cnt[hi], 1);
    atomicAdd(&dw[hi], __int_as_float(r.y));
  }
  __syncthreads();
  int a0 = cnt[2 * tid], a1 = cnt[2 * tid + 1];
  int sum2 = a0 + a1;
  ssum[tid] = sum2;
  __syncthreads();
  for (int off = 1; off < 256; off <<= 1) {
    int v = (tid >= off) ? ssum[tid - off] : 0;
    __syncthreads();
    ssum[tid] += v;
    __syncthreads();
  }
  int excl = ssum[tid] - sum2;
  pref[2 * tid] = excl;
  pref[2 * tid + 1] = excl + a0;
  __syncthreads();
#pragma unroll
  for (int k = 0; k < 2; ++k) {
    int hi = tid + k * 256;
    int node = (hi << 8) | lo;
    cur[hi] = s + pref[hi];
    if (node < n) {
      nodeRange[node] = make_int2(s + pref[hi], cnt[hi]);
      dinv[node] = rsqrtf(1.0f + dw[hi]);  // self-loop weight 1
    }
  }
  __syncthreads();
  for (int i = s + tid; i < t; i += 256) {
    int2 r = rec[i];
    int hi = ((uint32)r.x) >> 20;
    int p = atomicAdd(&cur[hi], 1);
    uint32 src = (uint32)(r.x & 0x1FFFF);
    uint32 wb = (uint32)bf16_of(__int_as_float(r.y)) & 0x7FFFu;
    edges[p] = (src << 15) | wb;
  }
}

// ---- MFMA GEMM with int8 per-row-scaled output, K=128 fixed.
template <int M, bool XF32, bool SWZ>
__global__ __launch_bounds__(256) void k_gemm_q(
    const void* __restrict__ Xv, const ushort_t* __restrict__ Wt,
    const float* __restrict__ dinv, unsigned char* __restrict__ Hb8,
    float* __restrict__ sc, int n) {
  __shared__ __align__(16) char smem[16384 + M * 256];
  char* Xs = smem;
  char* Ws = smem + 16384;
  const int tid = threadIdx.x;
  const int lane = tid & 63;
  const int w = tid >> 6;
  const int row0 = blockIdx.x * 64;

  {
    const uint4* src = (const uint4*)Wt;
    for (int idx = tid; idx < M * 16; idx += 256) {
      int r = idx >> 4, g = idx & 15;
      uint4 v = src[idx];
      *(uint4*)(Ws + ((r << 8) | ((g << 4) ^ ((r & 7) << 4)))) = v;
    }
  }
  if constexpr (XF32) {
    const float4* src = (const float4*)Xv;
    for (int idx = tid; idx < 64 * 16; idx += 256) {
      int r = idx >> 4, g = idx & 15;
      int grow = row0 + r;
      float4 va = make_float4(0.f, 0.f, 0.f, 0.f), vb = va;
      if (grow < n) {
        va = src[(size_t)grow * 32 + g * 2];
        vb = src[(size_t)grow * 32 + g * 2 + 1];
      }
      uint4 p;
      p.x = pack_bf16x2(va.x, va.y);
      p.y = pack_bf16x2(va.z, va.w);
      p.z = pack_bf16x2(vb.x, vb.y);
      p.w = pack_bf16x2(vb.z, vb.w);
      *(uint4*)(Xs + ((r << 8) | ((g << 4) ^ ((r & 7) << 4)))) = p;
    }
  } else {
    const uint4* src = (const uint4*)Xv;
    for (int idx = tid; idx < 64 * 16; idx += 256) {
      int r = idx >> 4, g = idx & 15;
      int grow = row0 + r;
      uint4 v = make_uint4(0u, 0u, 0u, 0u);
      if (grow < n) v = src[(size_t)grow * 16 + g];
      *(uint4*)(Xs + ((r << 8) | ((g << 4) ^ ((r & 7) << 4)))) = v;
    }
  }
  __syncthreads();

  constexpr int CT = M / 16;
  f32x4 acc[CT];
#pragma unroll
  for (int c = 0; c < CT; ++c) acc[c] = (f32x4){0.f, 0.f, 0.f, 0.f};

  const int arow = (w << 4) | (lane & 15);
  const int kb0 = (lane >> 4) << 4;
#pragma unroll
  for (int ks = 0; ks < 4; ++ks) {
    int kbyte = ks * 64 + kb0;
    bf16x8 a = *(const bf16x8*)(Xs + ((arow << 8) | (kbyte ^ ((arow & 7) << 4))));
#pragma unroll
    for (int c = 0; c < CT; ++c) {
      int brow = c * 16 + (lane & 15);
      bf16x8 b = *(const bf16x8*)(Ws + ((brow << 8) | (kbyte ^ ((brow & 7) << 4))));
      acc[c] = __builtin_amdgcn_mfma_f32_16x16x32_bf16(a, b, acc[c], 0, 0, 0);
    }
  }
  __syncthreads();

  // epilogue: dinv-scale, per-row int8 quantize (u8 = round(v*127/max)+128)
  const int gl = lane & 15;
  const int rbase = (w << 4) | ((lane >> 4) << 2);
  float mx[4] = {0.f, 0.f, 0.f, 0.f};
#pragma unroll
  for (int r = 0; r < 4; ++r) {
    int g = row0 + rbase + r;
    float dv = (g < n) ? dinv[g] : 0.f;
#pragma unroll
    for (int c = 0; c < CT; ++c) {
      acc[c][r] *= dv;
      mx[r] = fmaxf(mx[r], fabsf(acc[c][r]));
    }
  }
#pragma unroll
  for (int off = 1; off < 16; off <<= 1) {
#pragma unroll
    for (int r = 0; r < 4; ++r) mx[r] = fmaxf(mx[r], __shfl_xor(mx[r], off));
  }
  float inv[4];
#pragma unroll
  for (int r = 0; r < 4; ++r) {
    inv[r] = (mx[r] > 1e-30f) ? 127.0f / mx[r] : 0.f;
    int g = row0 + rbase + r;
    if (g < n && gl == 0) sc[g] = mx[r] * (1.0f / 127.0f);
  }

  if constexpr (SWZ) {  // M=128: direct stores, pos = gl*8 + c
#pragma unroll
    for (int r = 0; r < 4; ++r) {
      int g = row0 + rbase + r;
      if (g >= n) continue;
      uint32 lo = 0, hi = 0;
#pragma unroll
      for (int c = 0; c < 4; ++c) {
        uint32 q = (uint32)((int)rintf(acc[c][r] * inv[r]) + 128);
        lo |= q << (8 * c);
      }
#pragma unroll
      for (int c = 4; c < 8; ++c) {
        uint32 q = (uint32)((int)rintf(acc[c][r] * inv[r]) + 128);
        hi |= q << (8 * (c - 4));
      }
      ((uint2*)Hb8)[(size_t)g * 16 + gl] = make_uint2(lo, hi);
    }
  } else {  // M=64: standard order via LDS byte transpose
    unsigned char* Cs = (unsigned char*)smem;  // [64][68]
#pragma unroll
    for (int r = 0; r < 4; ++r) {
#pragma unroll
      for (int c = 0; c < CT; ++c) {
        int q = (int)rintf(acc[c][r] * inv[r]) + 128;
        Cs[(rbase + r) * 68 + c * 16 + gl] = (unsigned char)q;
      }
    }
    __syncthreads();
    for (int idx = tid; idx < 64 * (M / 4); idx += 256) {
      int r = idx / (M / 4), g = idx % (M / 4);
      int grow = row0 + r;
      if (grow < n)
        ((uint32*)Hb8)[(size_t)grow * (M / 4) + g] = *(const uint32*)(Cs + r * 68 + g * 4);
    }
  }
}

// ---- agg layer 1 (C=128, int8 swizzled table): one wave/node, 4 groups x 16 lanes.
// Edge list staged in REGISTERS (1 coalesced load) and broadcast via __shfl;
// lanes >= cnt hold 0 => weight 0 => padded slots contribute exactly zero, so the
// loop is branch-free over ceil(cnt/16) iterations. No LDS.
__global__ __launch_bounds__(TPB) void k_agg128(
    const uint2* __restrict__ t8, const float* __restrict__ scs,
    const uint32* __restrict__ edges, const int2* __restrict__ nodeRange,
    const float* __restrict__ dinv, const float* __restrict__ b1p,
    uint4* __restrict__ out, int n) {
  int node = (blockIdx.x * TPB + threadIdx.x) >> 6;
  if (node >= n) return;
  node = __builtin_amdgcn_readfirstlane(node);
  int lane = threadIdx.x & 63;
  int g = lane >> 4, gl = lane & 15;
  int2 nr = nodeRange[node];
  int s0 = nr.x, cnt = nr.y;
  int nS = min(cnt, 64);
  float di = dinv[node];
  uint32 ev = (lane < nS) ? edges[s0 + lane] : 0u;

  float a0, a1, a2, a3, a4, a5, a6, a7, beta;
  if (g == 0) {  // self loop (weight 1)
    uint2 u = t8[(size_t)node * 16 + gl];
    float al = scs[node];
    beta = al;
    a0 = ubf0(u.x) * al; a1 = ubf1(u.x) * al; a2 = ubf2(u.x) * al; a3 = ubf3(u.x) * al;
    a4 = ubf0(u.y) * al; a5 = ubf1(u.y) * al; a6 = ubf2(u.y) * al; a7 = ubf3(u.y) * al;
  } else {
    beta = 0.f;
    a0 = a1 = a2 = a3 = a4 = a5 = a6 = a7 = 0.f;
  }
  int iters = (nS + 15) >> 4;
  int k = g;
  for (int it = 0; it < iters; ++it, k += 16) {
    uint32 e0 = __shfl(ev, k), e1 = __shfl(ev, k + 4);
    uint32 e2 = __shfl(ev, k + 8), e3 = __shfl(ev, k + 12);
    int r0 = edge_src(e0), r1 = edge_src(e1), r2 = edge_src(e2), r3 = edge_src(e3);
    uint2 v0 = t8[(size_t)r0 * 16 + gl];
    uint2 v1 = t8[(size_t)r1 * 16 + gl];
    uint2 v2 = t8[(size_t)r2 * 16 + gl];
    uint2 v3 = t8[(size_t)r3 * 16 + gl];
    float al0 = edge_w(e0) * scs[r0], al1 = edge_w(e1) * scs[r1];
    float al2 = edge_w(e2) * scs[r2], al3 = edge_w(e3) * scs[r3];
    beta += (al0 + al1) + (al2 + al3);
    a0 = fmaf(ubf0(v0.x), al0, a0); a1 = fmaf(ubf1(v0.x), al0, a1);
    a2 = fmaf(ubf2(v0.x), al0, a2); a3 = fmaf(ubf3(v0.x), al0, a3);
    a4 = fmaf(ubf0(v0.y), al0, a4); a5 = fmaf(ubf1(v0.y), al0, a5);
    a6 = fmaf(ubf2(v0.y), al0, a6); a7 = fmaf(ubf3(v0.y), al0, a7);
    a0 = fmaf(ubf0(v1.x), al1, a0); a1 = fmaf(ubf1(v1.x), al1, a1);
    a2 = fmaf(ubf2(v1.x), al1, a2); a3 = fmaf(ubf3(v1.x), al1, a3);
    a4 = fmaf(ubf0(v1.y), al1, a4); a5 = fmaf(ubf1(v1.y), al1, a5);
    a6 = fmaf(ubf2(v1.y), al1, a6); a7 = fmaf(ubf3(v1.y), al1, a7);
    a0 = fmaf(ubf0(v2.x), al2, a0); a1 = fmaf(ubf1(v2.x), al2, a1);
    a2 = fmaf(ubf2(v2.x), al2, a2); a3 = fmaf(ubf3(v2.x), al2, a3);
    a4 = fmaf(ubf0(v2.y), al2, a4); a5 = fmaf(ubf1(v2.y), al2, a5);
    a6 = fmaf(ubf2(v2.y), al2, a6); a7 = fmaf(ubf3(v2.y), al2, a7);
    a0 = fmaf(ubf0(v3.x), al3, a0); a1 = fmaf(ubf1(v3.x), al3, a1);
    a2 = fmaf(ubf2(v3.x), al3, a2); a3 = fmaf(ubf3(v3.x), al3, a3);
    a4 = fmaf(ubf0(v3.y), al3, a4); a5 = fmaf(ubf1(v3.y), al3, a5);
    a6 = fmaf(ubf2(v3.y), al3, a6); a7 = fmaf(ubf3(v3.y), al3, a7);
  }
  for (int kk = s0 + 64 + g; kk < s0 + cnt; kk += 4) {  // rare deg>64 tail
    uint32 e0 = edges[kk];
    int r0 = edge_src(e0);
    uint2 v0 = t8[(size_t)r0 * 16 + gl];
    float al0 = edge_w(e0) * scs[r0];
    beta += al0;
    a0 = fmaf(ubf0(v0.x), al0, a0); a1 = fmaf(ubf1(v0.x), al0, a1);
    a2 = fmaf(ubf2(v0.x), al0, a2); a3 = fmaf(ubf3(v0.x), al0, a3);
    a4 = fmaf(ubf0(v0.y), al0, a4); a5 = fmaf(ubf1(v0.y), al0, a5);
    a6 = fmaf(ubf2(v0.y), al0, a6); a7 = fmaf(ubf3(v0.y), al0, a7);
  }
  a0 += __shfl_xor(a0, 16); a1 += __shfl_xor(a1, 16);
  a2 += __shfl_xor(a2, 16); a3 += __shfl_xor(a3, 16);
  a4 += __shfl_xor(a4, 16); a5 += __shfl_xor(a5, 16);
  a6 += __shfl_xor(a6, 16); a7 += __shfl_xor(a7, 16);
  beta += __shfl_xor(beta, 16);
  a0 += __shfl_xor(a0, 32); a1 += __shfl_xor(a1, 32);
  a2 += __shfl_xor(a2, 32); a3 += __shfl_xor(a3, 32);
  a4 += __shfl_xor(a4, 32); a5 += __shfl_xor(a5, 32);
  a6 += __shfl_xor(a6, 32); a7 += __shfl_xor(a7, 32);
  beta += __shfl_xor(beta, 32);
  if (g == 0) {
    float corr = 128.0f * beta;
    float4 bb0 = ((const float4*)b1p)[gl * 2];
    float4 bb1 = ((const float4*)b1p)[gl * 2 + 1];
    float o0 = fmaxf(fmaf(a0 - corr, di, bb0.x), 0.f);
    float o1 = fmaxf(fmaf(a1 - corr, di, bb0.y), 0.f);
    float o2 = fmaxf(fmaf(a2 - corr, di, bb0.z), 0.f);
    float o3 = fmaxf(fmaf(a3 - corr, di, bb0.w), 0.f);
    float o4 = fmaxf(fmaf(a4 - corr, di, bb1.x), 0.f);
    float o5 = fmaxf(fmaf(a5 - corr, di, bb1.y), 0.f);
    float o6 = fmaxf(fmaf(a6 - corr, di, bb1.z), 0.f);
    float o7 = fmaxf(fmaf(a7 - corr, di, bb1.w), 0.f);
    uint4 ob;
    ob.x = pack_bf16x2(o0, o1);
    ob.y = pack_bf16x2(o2, o3);
    ob.z = pack_bf16x2(o4, o5);
    ob.w = pack_bf16x2(o6, o7);
    out[(size_t)node * 16 + gl] = ob;
  }
}

// ---- agg layer 2 (C=64, int8 standard table): 8 groups x 8 lanes, register+shfl
// edge staging, branch-free padded loop; fp32 out.
__global__ __launch_bounds__(TPB) void k_agg64(
    const uint2* __restrict__ t8, const float* __restrict__ scs,
    const uint32* __restrict__ edges, const int2* __restrict__ nodeRange,
    const float* __restrict__ dinv, const float* __restrict__ bias,
    float4* __restrict__ out, int n) {
  int node = (blockIdx.x * TPB + threadIdx.x) >> 6;
  if (node >= n) return;
  node = __builtin_amdgcn_readfirstlane(node);
  int lane = threadIdx.x & 63;
  int g = lane >> 3, gl = lane & 7;
  int2 nr = nodeRange[node];
  int s0 = nr.x, cnt = nr.y;
  int nS = min(cnt, 64);
  float di = dinv[node];
  uint32 ev = (lane < nS) ? edges[s0 + lane] : 0u;

  float a0, a1, a2, a3, a4, a5, a6, a7, beta;
  if (g == 0) {  // self loop
    uint2 u = t8[(size_t)node * 8 + gl];
    float al = scs[node];
    beta = al;
    a0 = ubf0(u.x) * al; a1 = ubf1(u.x) * al; a2 = ubf2(u.x) * al; a3 = ubf3(u.x) * al;
    a4 = ubf0(u.y) * al; a5 = ubf1(u.y) * al; a6 = ubf2(u.y) * al; a7 = ubf3(u.y) * al;
  } else {
    beta = 0.f;
    a0 = a1 = a2 = a3 = a4 = a5 = a6 = a7 = 0.f;
  }
  int iters = (nS + 15) >> 4;
  int k = g;
  for (int it = 0; it < iters; ++it, k += 16) {
    uint32 e0 = __shfl(ev, k), e1 = __shfl(ev, k + 8);
    int r0 = edge_src(e0), r1 = edge_src(e1);
    uint2 v0 = t8[(size_t)r0 * 8 + gl];
    uint2 v1 = t8[(size_t)r1 * 8 + gl];
    float al0 = edge_w(e0) * scs[r0], al1 = edge_w(e1) * scs[r1];
    beta += al0 + al1;
    a0 = fmaf(ubf0(v0.x), al0, a0); a1 = fmaf(ubf1(v0.x), al0, a1);
    a2 = fmaf(ubf2(v0.x), al0, a2); a3 = fmaf(ubf3(v0.x), al0, a3);
    a4 = fmaf(ubf0(v0.y), al0, a4); a5 = fmaf(ubf1(v0.y), al0, a5);
    a6 = fmaf(ubf2(v0.y), al0, a6); a7 = fmaf(ubf3(v0.y), al0, a7);
    a0 = fmaf(ubf0(v1.x), al1, a0); a1 = fmaf(ubf1(v1.x), al1, a1);
    a2 = fmaf(ubf2(v1.x), al1, a2); a3 = fmaf(ubf3(v1.x), al1, a3);
    a4 = fmaf(ubf0(v1.y), al1, a4); a5 = fmaf(ubf1(v1.y), al1, a5);
    a6 = fmaf(ubf2(v1.y), al1, a6); a7 = fmaf(ubf3(v1.y), al1, a7);
  }
  for (int kk = s0 + 64 + g; kk < s0 + cnt; kk += 8) {  // rare deg>64 tail
    uint32 e0 = edges[kk];
    int r0 = edge_src(e0);
    uint2 v0 = t8[(size_t)r0 * 8 + gl];
    float al0 = edge_w(e0) * scs[r0];
    beta += al0;
    a0 = fmaf(ubf0(v0.x), al0, a0); a1 = fmaf(ubf1(v0.x), al0, a1);
    a2 = fmaf(ubf2(v0.x), al0, a2); a3 = fmaf(ubf3(v0.x), al0, a3);
    a4 = fmaf(ubf0(v0.y), al0, a4); a5 = fmaf(ubf1(v0.y), al0, a5);
    a6 = fmaf(ubf2(v0.y), al0, a6); a7 = fmaf(ubf3(v0.y), al0, a7);
  }
#pragma unroll
  for (int off = 8; off <= 32; off <<= 1) {
    a0 += __shfl_xor(a0, off); a1 += __shfl_xor(a1, off);
    a2 += __shfl_xor(a2, off); a3 += __shfl_xor(a3, off);
    a4 += __shfl_xor(a4, off); a5 += __shfl_xor(a5, off);
    a6 += __shfl_xor(a6, off); a7 += __shfl_xor(a7, off);
    beta += __shfl_xor(beta, off);
  }
  if (g == 0) {
    float corr = 128.0f * beta;
    float4 bb0 = ((const float4*)bias)[gl * 2];
    float4 bb1 = ((const float4*)bias)[gl * 2 + 1];
    float4 o0, o1;
    o0.x = fmaxf(fmaf(a0 - corr, di, bb0.x), 0.f);
    o0.y = fmaxf(fmaf(a1 - corr, di, bb0.y), 0.f);
    o0.z = fmaxf(fmaf(a2 - corr, di, bb0.z), 0.f);
    o0.w = fmaxf(fmaf(a3 - corr, di, bb0.w), 0.f);
    o1.x = fmaxf(fmaf(a4 - corr, di, bb1.x), 0.f);
    o1.y = fmaxf(fmaf(a5 - corr, di, bb1.y), 0.f);
    o1.z = fmaxf(fmaf(a6 - corr, di, bb1.z), 0.f);
    o1.w = fmaxf(fmaf(a7 - corr, di, bb1.w), 0.f);
    out[(size_t)node * 16 + gl * 2] = o0;
    out[(size_t)node * 16 + gl * 2 + 1] = o1;
  }
}

extern "C" void kernel_launch(void* const* d_in, const int* in_sizes, int n_in,
                              void* d_out, int out_size, void* d_ws, size_t ws_size,
                              hipStream_t stream) {
  const float* x  = (const float*)d_in[0];
  const int*   ei = (const int*)d_in[1];
  const float* ew = (const float*)d_in[2];
  const float* W1 = (const float*)d_in[3];
  const float* b1 = (const float*)d_in[4];
  const float* W2 = (const float*)d_in[5];
  const float* b2 = (const float*)d_in[6];
  float* out = (float*)d_out;

  constexpr int IN_C = 128, HID = 128, OUTC = 64;
  const int n = in_sizes[0] / IN_C;
  const int e = in_sizes[2];
  const int* rowp = ei;
  const int* colp = ei + e;

  auto cdiv = [](long a, long b) { return (int)((a + b - 1) / b); };
  auto align = [](size_t v) { return (v + 255) & ~(size_t)255; };

  char* ws = (char*)d_ws;
  size_t o = 0;
  int*      blockhist = (int*)(ws + o);      o = align(o + (size_t)NB * B1 * 4);
  int*      bsum      = (int*)(ws + o);      o = align(o + 4096);
  float*    dinv      = (float*)(ws + o);    o = align(o + (size_t)n * 4);
  int2*     nodeRange = (int2*)(ws + o);     o = align(o + (size_t)n * 8);
  ushort_t* Wt1       = (ushort_t*)(ws + o); o = align(o + (size_t)HID * IN_C * 2);
  ushort_t* Wt2       = (ushort_t*)(ws + o); o = align(o + (size_t)OUTC * HID * 2);
  float*    b1p       = (float*)(ws + o);    o = align(o + 512);
  float*    sc1       = (float*)(ws + o);    o = align(o + (size_t)n * 4);
  float*    sc2       = (float*)(ws + o);    o = align(o + (size_t)n * 4);
  int2*     rec       = (int2*)(ws + o);     o = align(o + (size_t)e * 8);
  uint32*   edges     = (uint32*)(ws + o);   o = align(o + (size_t)e * 4);
  unsigned char* hs1b8 = (unsigned char*)(ws + o); o = align(o + (size_t)n * HID);  // int8 swz
  uint4*    o1b       = (uint4*)(ws + o);    o = align(o + (size_t)n * HID * 2);    // bf16 swz
  unsigned char* hs2b8 = hs1b8;  // int8 [n][64]; hs1b8 dead after agg128

  const int chunk = cdiv(e, B1);
  const int nscan = NB * B1;  // 65536

  // ---- preprocessing: CSR build (zero global atomics), W/bias prep folded ----
  rx_hist<<<B1, 256, 0, stream>>>(colp, blockhist, e, chunk, W1, Wt1, W2, Wt2, b1, b1p);
  k_scan1<<<nscan / 1024, 256, 0, stream>>>(blockhist, bsum, nscan);
  k_scan2<<<1, 256, 0, stream>>>(bsum, nscan / 1024);
  rx_scatter1<<<B1, 256, 0, stream>>>(rowp, colp, ew, blockhist, bsum, rec, e, chunk);
  rx_build<<<NB, 256, 0, stream>>>(rec, blockhist, bsum, nodeRange, dinv, edges, n, e);

  // ---- layer 1 ----
  k_gemm_q<HID, true, true><<<cdiv(n, 64), 256, 0, stream>>>(x, Wt1, dinv, hs1b8, sc1, n);
  k_agg128<<<cdiv(n, 4), TPB, 0, stream>>>((const uint2*)hs1b8, sc1, edges, nodeRange,
                                           dinv, b1p, o1b, n);

  // ---- layer 2 ----
  k_gemm_q<OUTC, false, false><<<cdiv(n, 64), 256, 0, stream>>>(o1b, Wt2, dinv, hs2b8, sc2, n);
  k_agg64<<<cdiv(n, 4), TPB, 0, stream>>>((const uint2*)hs2b8, sc2, edges, nodeRange,
                                          dinv, b2, (float4*)out, n);
}